// Round 3
// baseline (1840.953 us; speedup 1.0000x reference)
//
#include <hip/hip_runtime.h>

#define Bn 4
#define Tn 1024
#define Cn 768
#define Hn 12
#define Dn 4
#define Vn 32000
#define BTn (Bn*Tn)

typedef __attribute__((ext_vector_type(8))) short short8;
typedef __attribute__((ext_vector_type(4))) float f32x4;

__device__ __forceinline__ unsigned short f2bf(float f) {
  union { float f; unsigned u; } v; v.f = f;
  unsigned r = v.u + 0x7fffu + ((v.u >> 16) & 1u);
  return (unsigned short)(r >> 16);
}

__device__ __forceinline__ void gload_lds16(const void* g, void* l) {
  __builtin_amdgcn_global_load_lds(
      (const __attribute__((address_space(1))) void*)g,
      (__attribute__((address_space(3))) void*)l, 16, 0, 0);
}

// ---------------- transpose fp32 [K][N] -> bf16 [N][K] ----------------
__global__ __launch_bounds__(256)
void transpose_bf16_kernel(const float* __restrict__ src, unsigned short* __restrict__ dst,
                           int K, int N) {
  __shared__ float tile[32][33];
  const int tx = threadIdx.x, ty = threadIdx.y;
  const int n0 = blockIdx.x * 32, k0 = blockIdx.y * 32;
#pragma unroll
  for (int i = 0; i < 4; ++i)
    tile[ty + i*8][tx] = src[(size_t)(k0 + ty + i*8) * N + n0 + tx];
  __syncthreads();
#pragma unroll
  for (int i = 0; i < 4; ++i)
    dst[(size_t)(n0 + ty + i*8) * K + k0 + tx] = f2bf(tile[tx][ty + i*8]);
}

// ---------------- embedding: h = wordemb[x] + posemb[t], + bf16 copy ----------------
__global__ __launch_bounds__(256)
void embed_kernel(const int* __restrict__ x, const float* __restrict__ wordemb,
                  const float* __restrict__ posemb, float* __restrict__ h,
                  unsigned short* __restrict__ hb) {
  int i4 = blockIdx.x * 256 + threadIdx.x;        // over BTn*Cn/4, exact grid
  int row = i4 / (Cn/4), c4 = i4 % (Cn/4);
  int t = row & (Tn - 1);
  int tok = x[row];
  float4 a = ((const float4*)wordemb)[(size_t)tok * (Cn/4) + c4];
  float4 p = ((const float4*)posemb)[(size_t)t * (Cn/4) + c4];
  float4 s; s.x = a.x+p.x; s.y = a.y+p.y; s.z = a.z+p.z; s.w = a.w+p.w;
  ((float4*)h)[i4] = s;
  ushort4 u; u.x = f2bf(s.x); u.y = f2bf(s.y); u.z = f2bf(s.z); u.w = f2bf(s.w);
  ((ushort4*)hb)[i4] = u;
}

// ---------------- bf16 MFMA GEMM (m97 structure): C = A[M,K] * Bt[N,K]^T -------------
// 128x128 tile, BK=32, 4 waves. global_load_lds 16B staging into LINEAR LDS.
// grid = (M/128, N/128): consecutive blocks share the B panel (L2 reuse).
__global__ __launch_bounds__(256)
void gemm_bf16_kernel(const unsigned short* __restrict__ A, const unsigned short* __restrict__ Bt,
                      const float* __restrict__ bias, float* __restrict__ Cf,
                      unsigned short* __restrict__ Cb, int M, int N, int K, int relu) {
  __shared__ unsigned short As[128*32];
  __shared__ unsigned short Bs[128*32];
  const int t = threadIdx.x;
  const int by = blockIdx.x, bx = blockIdx.y;   // by = M-tile, bx = N-tile
  const int lane = t & 63, w = t >> 6;
  const int wr = w >> 1, wc = w & 1;
  const int lr = lane & 15, lq = lane >> 4;

  f32x4 acc[4][4];
#pragma unroll
  for (int i = 0; i < 4; ++i)
#pragma unroll
    for (int j = 0; j < 4; ++j)
      acc[i][j] = (f32x4){0.f, 0.f, 0.f, 0.f};

  // staging: wave w owns rows w*32..w*32+31 of each tile; lane l -> row l/4, col (l&3)*8
  const int sl_row = lane >> 2;
  const int sl_col = (lane & 3) * 8;
  const unsigned short* agl = A  + (size_t)(by*128 + w*32 + sl_row) * K + sl_col;
  const unsigned short* bgl = Bt + (size_t)(bx*128 + w*32 + sl_row) * K + sl_col;
  unsigned short* asw = &As[(w*32)*32];   // wave-uniform LDS base
  unsigned short* bsw = &Bs[(w*32)*32];

  for (int k0 = 0; k0 < K; k0 += 32) {
    __syncthreads();
    gload_lds16(agl + k0,            asw);
    gload_lds16(agl + k0 + 16*(size_t)K, asw + 16*32);
    gload_lds16(bgl + k0,            bsw);
    gload_lds16(bgl + k0 + 16*(size_t)K, bsw + 16*32);
    __syncthreads();
    short8 af[4], bfr[4];
#pragma unroll
    for (int i = 0; i < 4; ++i) af[i]  = *(const short8*)&As[(wr*64 + i*16 + lr)*32 + lq*8];
#pragma unroll
    for (int j = 0; j < 4; ++j) bfr[j] = *(const short8*)&Bs[(wc*64 + j*16 + lr)*32 + lq*8];
#pragma unroll
    for (int i = 0; i < 4; ++i)
#pragma unroll
      for (int j = 0; j < 4; ++j)
        acc[i][j] = __builtin_amdgcn_mfma_f32_16x16x32_bf16(af[i], bfr[j], acc[i][j], 0, 0, 0);
  }

#pragma unroll
  for (int i = 0; i < 4; ++i)
#pragma unroll
    for (int j = 0; j < 4; ++j)
#pragma unroll
      for (int r = 0; r < 4; ++r) {
        int grow = by*128 + wr*64 + i*16 + lq*4 + r;   // C/D: row=(lane>>4)*4+reg
        int gcol = bx*128 + wc*64 + j*16 + lr;         //      col=lane&15
        float v = acc[i][j][r];
        if (bias) v += bias[gcol];
        if (relu) v = fmaxf(v, 0.f);
        size_t idx = (size_t)grow * N + gcol;
        if (Cf) Cf[idx] = v;
        if (Cb) Cb[idx] = f2bf(v);
      }
}

// ---------------- vT: qkvb V-section [BT][2304] -> vT[b][h][d][t] (bf16) -------------
__global__ __launch_bounds__(256)
void vT_kernel(const unsigned short* __restrict__ qkvb, unsigned short* __restrict__ vT) {
  const int tb = blockIdx.x, hh = blockIdx.y, b = blockIdx.z;
  const int t = threadIdx.x;
  __shared__ unsigned short tile[64][65];
  const int r = t >> 2, c = t & 3;
  const unsigned short* src = qkvb + (size_t)(b*Tn + tb*64 + r) * 2304 + 1536 + hh*64 + c*16;
  short8 v0 = *(const short8*)src;
  short8 v1 = *(const short8*)(src + 8);
#pragma unroll
  for (int j = 0; j < 8; ++j) { tile[r][c*16 + j] = (unsigned short)v0[j]; tile[r][c*16 + 8 + j] = (unsigned short)v1[j]; }
  __syncthreads();
  unsigned short o[16];
#pragma unroll
  for (int j = 0; j < 16; ++j) o[j] = tile[c*16 + j][r];
  unsigned short* dst = vT + ((size_t)((b*Hn + hh)*64 + r)) * Tn + tb*64 + c*16;
  *(ushort4*)(dst)      = *(ushort4*)&o[0];
  *(ushort4*)(dst + 4)  = *(ushort4*)&o[4];
  *(ushort4*)(dst + 8)  = *(ushort4*)&o[8];
  *(ushort4*)(dst + 12) = *(ushort4*)&o[12];
}

// ---------------- MFMA flash attention: bf16 in/out, fp32 accum ----------------------
__global__ __launch_bounds__(256)
void attn_mfma_kernel(const unsigned short* __restrict__ qkvb,
                      const unsigned short* __restrict__ vT,
                      unsigned short* __restrict__ attb) {
  const int qb = blockIdx.x, hh = blockIdx.y, b = blockIdx.z;
  const int t = threadIdx.x;
  const int lane = t & 63, w = t >> 6;
  const int lr = lane & 15, lg = lane >> 4;
  const float scale = 0.03608439182435161f;   // 1/sqrt(768): ref scales by sqrt(C)

  __shared__ unsigned short Ks[64*64];        // [k][64d], slots XOR-swizzled
  __shared__ unsigned short Vs[64*64];        // [d][64k], slots XOR-swizzled
  __shared__ unsigned short Ps[4][16][72];    // per-wave P tile, +8 pad

  const unsigned short* qsrc = qkvb + (size_t)(b*Tn + qb*64 + w*16 + lr)*2304 + hh*64 + lg*8;
  short8 qa0 = *(const short8*)(qsrc);
  short8 qa1 = *(const short8*)(qsrc + 32);

  f32x4 acc[4];
#pragma unroll
  for (int dt = 0; dt < 4; ++dt) acc[dt] = (f32x4){0.f,0.f,0.f,0.f};
  float m_run[4], l_run[4];
#pragma unroll
  for (int r = 0; r < 4; ++r) { m_run[r] = -1e30f; l_run[r] = 0.f; }

  const int sr = t >> 2, c2 = t & 3;          // staging: row, 32B chunk

  for (int kvb = 0; kvb <= qb; ++kvb) {
    __syncthreads();
    {
      const unsigned short* ksrc = qkvb + (size_t)(b*Tn + kvb*64 + sr)*2304 + 768 + hh*64 + c2*16;
      short8 k0 = *(const short8*)ksrc;
      short8 k1 = *(const short8*)(ksrc + 8);
      const unsigned short* vsrc = vT + ((size_t)((b*Hn + hh)*64 + sr))*Tn + kvb*64 + c2*16;
      short8 vv0 = *(const short8*)vsrc;
      short8 vv1 = *(const short8*)(vsrc + 8);
      int s0 = (2*c2) ^ (sr & 7), s1 = (2*c2 + 1) ^ (sr & 7);
      *(short8*)&Ks[sr*64 + s0*8] = k0;
      *(short8*)&Ks[sr*64 + s1*8] = k1;
      *(short8*)&Vs[sr*64 + s0*8] = vv0;
      *(short8*)&Vs[sr*64 + s1*8] = vv1;
    }
    __syncthreads();

    f32x4 s[4];
#pragma unroll
    for (int kt = 0; kt < 4; ++kt) {
      int krow = kt*16 + lr;
      short8 kf0 = *(const short8*)&Ks[krow*64 + ((0 + lg) ^ (krow & 7))*8];
      short8 kf1 = *(const short8*)&Ks[krow*64 + ((4 + lg) ^ (krow & 7))*8];
      f32x4 a = (f32x4){0.f,0.f,0.f,0.f};
      a = __builtin_amdgcn_mfma_f32_16x16x32_bf16(qa0, kf0, a, 0, 0, 0);
      a = __builtin_amdgcn_mfma_f32_16x16x32_bf16(qa1, kf1, a, 0, 0, 0);
      s[kt] = a;
    }
    const bool diag = (kvb == qb);
#pragma unroll
    for (int kt = 0; kt < 4; ++kt)
#pragma unroll
      for (int r = 0; r < 4; ++r) {
        float v = s[kt][r] * scale;
        if (diag && (kt*16 + lr > w*16 + lg*4 + r)) v = -1e30f;
        s[kt][r] = v;
      }
#pragma unroll
    for (int r = 0; r < 4; ++r) {
      float m = fmaxf(fmaxf(s[0][r], s[1][r]), fmaxf(s[2][r], s[3][r]));
      m = fmaxf(m, __shfl_xor(m, 1));
      m = fmaxf(m, __shfl_xor(m, 2));
      m = fmaxf(m, __shfl_xor(m, 4));
      m = fmaxf(m, __shfl_xor(m, 8));
      float mn = fmaxf(m_run[r], m);
      float corr = __expf(m_run[r] - mn);
      m_run[r] = mn;
      float ps = 0.f;
#pragma unroll
      for (int kt = 0; kt < 4; ++kt) {
        float p = __expf(s[kt][r] - mn);
        s[kt][r] = p;
        ps += p;
      }
      ps += __shfl_xor(ps, 1);
      ps += __shfl_xor(ps, 2);
      ps += __shfl_xor(ps, 4);
      ps += __shfl_xor(ps, 8);
      l_run[r] = l_run[r] * corr + ps;
#pragma unroll
      for (int dt = 0; dt < 4; ++dt) acc[dt][r] *= corr;
    }
#pragma unroll
    for (int kt = 0; kt < 4; ++kt)
#pragma unroll
      for (int r = 0; r < 4; ++r)
        Ps[w][lg*4 + r][kt*16 + lr] = f2bf(s[kt][r]);
    short8 pa0 = *(const short8*)&Ps[w][lr][lg*8];
    short8 pa1 = *(const short8*)&Ps[w][lr][32 + lg*8];
#pragma unroll
    for (int dt = 0; dt < 4; ++dt) {
      int drow = dt*16 + lr;
      short8 vf0 = *(const short8*)&Vs[drow*64 + ((0 + lg) ^ (drow & 7))*8];
      short8 vf1 = *(const short8*)&Vs[drow*64 + ((4 + lg) ^ (drow & 7))*8];
      acc[dt] = __builtin_amdgcn_mfma_f32_16x16x32_bf16(pa0, vf0, acc[dt], 0, 0, 0);
      acc[dt] = __builtin_amdgcn_mfma_f32_16x16x32_bf16(pa1, vf1, acc[dt], 0, 0, 0);
    }
  }

  unsigned short* obase = attb + (size_t)(b*Tn + qb*64 + w*16)*768 + hh*64;
#pragma unroll
  for (int dt = 0; dt < 4; ++dt)
#pragma unroll
    for (int r = 0; r < 4; ++r) {
      float v = acc[dt][r] / l_run[r];
      obase[(size_t)(lg*4 + r)*768 + dt*16 + lr] = f2bf(v);
    }
}

// ---------------- residual + layernorm: h = h + LN(x)*g+b ; also bf16 copy ----------
__global__ __launch_bounds__(256)
void ln_res_kernel(const float* __restrict__ x, float* __restrict__ h,
                   unsigned short* __restrict__ hb, const float* __restrict__ g,
                   const float* __restrict__ bb) {
  const int row = blockIdx.x, tid = threadIdx.x;
  const float* xr = x + (size_t)row * Cn;
  float v[3], s1 = 0.f, s2 = 0.f;
#pragma unroll
  for (int j = 0; j < 3; ++j) { v[j] = xr[tid + j*256]; s1 += v[j]; s2 += v[j]*v[j]; }
  __shared__ float r1[256], r2[256];
  r1[tid] = s1; r2[tid] = s2;
  __syncthreads();
  for (int s = 128; s > 0; s >>= 1) {
    if (tid < s) { r1[tid] += r1[tid+s]; r2[tid] += r2[tid+s]; }
    __syncthreads();
  }
  float mu = r1[0] * (1.f/768.f);
  float var = r2[0] * (1.f/768.f) - mu*mu;
  float rs = rsqrtf(var + 1e-5f);
  float* hr = h + (size_t)row * Cn;
  unsigned short* hbr = hb + (size_t)row * Cn;
#pragma unroll
  for (int j = 0; j < 3; ++j) {
    int c = tid + j*256;
    float y = hr[c] + (v[j]-mu)*rs*g[c] + bb[c];
    hr[c] = y;
    hbr[c] = f2bf(y);
  }
}

// ---------------- loss: per-row logsumexp - logit[y], then deterministic mean -------
__global__ __launch_bounds__(256)
void loss_row_kernel(const float* __restrict__ logits, const int* __restrict__ y,
                     float* __restrict__ loss_rows) {
  const int row = blockIdx.x, tid = threadIdx.x;
  const float* lg = logits + (size_t)row * Vn;
  __shared__ float red[256];
  float mx = -1e30f;
  for (int j = 0; j < Vn/256; ++j) mx = fmaxf(mx, lg[tid + j*256]);
  red[tid] = mx; __syncthreads();
  for (int s = 128; s > 0; s >>= 1) {
    if (tid < s) red[tid] = fmaxf(red[tid], red[tid+s]);
    __syncthreads();
  }
  mx = red[0]; __syncthreads();
  float sum = 0.f;
  for (int j = 0; j < Vn/256; ++j) sum += __expf(lg[tid + j*256] - mx);
  red[tid] = sum; __syncthreads();
  for (int s = 128; s > 0; s >>= 1) {
    if (tid < s) red[tid] += red[tid+s];
    __syncthreads();
  }
  if (tid == 0) {
    float lse = mx + __logf(red[0]);
    loss_rows[row] = lse - lg[y[row]];
  }
}

__global__ __launch_bounds__(256)
void loss_reduce_kernel(const float* __restrict__ loss_rows, float* __restrict__ out) {
  const int tid = threadIdx.x;
  float s = 0.f;
  for (int j = 0; j < BTn/256; ++j) s += loss_rows[tid + j*256];
  __shared__ float red[256];
  red[tid] = s; __syncthreads();
  for (int st = 128; st > 0; st >>= 1) {
    if (tid < st) red[tid] += red[tid+st];
    __syncthreads();
  }
  if (tid == 0) out[0] = red[0] * (1.f/(float)BTn);
}

// =====================================================================================
extern "C" void kernel_launch(void* const* d_in, const int* in_sizes, int n_in,
                              void* d_out, int out_size, void* d_ws, size_t ws_size,
                              hipStream_t stream) {
  const int*   x       = (const int*)  d_in[0];
  const int*   y       = (const int*)  d_in[1];
  const float* wordemb = (const float*)d_in[2];
  const float* posemb  = (const float*)d_in[3];
  const float* Wq      = (const float*)d_in[4];
  const float* Wk      = (const float*)d_in[5];
  const float* Wv      = (const float*)d_in[6];
  const float* Wo      = (const float*)d_in[7];
  const float* bo      = (const float*)d_in[8];
  const float* ln1_g   = (const float*)d_in[9];
  const float* ln1_b   = (const float*)d_in[10];
  const float* W1      = (const float*)d_in[11];
  const float* b1      = (const float*)d_in[12];
  const float* W2      = (const float*)d_in[13];
  const float* b2      = (const float*)d_in[14];
  const float* ln2_g   = (const float*)d_in[15];
  const float* ln2_b   = (const float*)d_in[16];
  const float* Wl      = (const float*)d_in[17];
  const float* bl      = (const float*)d_in[18];

  char* ws = (char*)d_ws;
  size_t off = 0;
  auto alloc = [&](size_t bytes) -> char* {
    char* p = ws + off;
    off += (bytes + 255) & ~(size_t)255;
    return p;
  };
  unsigned short* wqkvT = (unsigned short*)alloc((size_t)Dn*2304*768*2);
  unsigned short* woT   = (unsigned short*)alloc((size_t)Dn*768*768*2);
  unsigned short* w1T   = (unsigned short*)alloc((size_t)Dn*3072*768*2);
  unsigned short* w2T   = (unsigned short*)alloc((size_t)Dn*768*3072*2);
  unsigned short* wlT   = (unsigned short*)alloc((size_t)Vn*768*2);
  float*          h     = (float*)alloc((size_t)BTn*Cn*4);
  unsigned short* hb    = (unsigned short*)alloc((size_t)BTn*Cn*2);
  unsigned short* qkvb  = (unsigned short*)alloc((size_t)BTn*3072*2);  // also ff1b alias
  unsigned short* vTb   = (unsigned short*)alloc((size_t)Bn*Hn*64*Tn*2);
  unsigned short* attb  = (unsigned short*)alloc((size_t)BTn*Cn*2);
  float*          tmp   = (float*)alloc((size_t)BTn*Cn*4);       // attout / ff2
  float*          loss_rows = (float*)alloc((size_t)BTn*4);
  unsigned short* ff1b  = qkvb;  // alias: qkv dead once attn done

  dim3 tb(32, 8);
  for (int d = 0; d < Dn; ++d) {
    transpose_bf16_kernel<<<dim3(24,24), tb, 0, stream>>>(Wq + (size_t)d*Cn*Cn, wqkvT + (size_t)d*2304*768,            Cn, Cn);
    transpose_bf16_kernel<<<dim3(24,24), tb, 0, stream>>>(Wk + (size_t)d*Cn*Cn, wqkvT + (size_t)d*2304*768 + 768*768,  Cn, Cn);
    transpose_bf16_kernel<<<dim3(24,24), tb, 0, stream>>>(Wv + (size_t)d*Cn*Cn, wqkvT + (size_t)d*2304*768 + 1536*768, Cn, Cn);
    transpose_bf16_kernel<<<dim3(24,24), tb, 0, stream>>>(Wo + (size_t)d*Cn*Cn, woT + (size_t)d*768*768,  Cn, Cn);
    transpose_bf16_kernel<<<dim3(96,24), tb, 0, stream>>>(W1 + (size_t)d*768*3072, w1T + (size_t)d*3072*768, 768, 3072);
    transpose_bf16_kernel<<<dim3(24,96), tb, 0, stream>>>(W2 + (size_t)d*3072*768, w2T + (size_t)d*768*3072, 3072, 768);
  }
  transpose_bf16_kernel<<<dim3(1000,24), tb, 0, stream>>>(Wl, wlT, 768, Vn);

  embed_kernel<<<(BTn*Cn/4)/256, 256, 0, stream>>>(x, wordemb, posemb, h, hb);

  for (int d = 0; d < Dn; ++d) {
    gemm_bf16_kernel<<<dim3(BTn/128, 2304/128), 256, 0, stream>>>(
        hb, wqkvT + (size_t)d*2304*768, nullptr, nullptr, qkvb, BTn, 2304, 768, 0);
    vT_kernel<<<dim3(Tn/64, Hn, Bn), 256, 0, stream>>>(qkvb, vTb);
    attn_mfma_kernel<<<dim3(Tn/64, Hn, Bn), 256, 0, stream>>>(qkvb, vTb, attb);
    gemm_bf16_kernel<<<dim3(BTn/128, 768/128), 256, 0, stream>>>(
        attb, woT + (size_t)d*768*768, bo + (size_t)d*768, tmp, nullptr, BTn, 768, 768, 0);
    ln_res_kernel<<<BTn, 256, 0, stream>>>(tmp, h, hb, ln1_g + (size_t)d*768, ln1_b + (size_t)d*768);
    gemm_bf16_kernel<<<dim3(BTn/128, 3072/128), 256, 0, stream>>>(
        hb, w1T + (size_t)d*3072*768, b1 + (size_t)d*3072, nullptr, ff1b, BTn, 3072, 768, 1);
    gemm_bf16_kernel<<<dim3(BTn/128, 768/128), 256, 0, stream>>>(
        ff1b, w2T + (size_t)d*768*3072, b2 + (size_t)d*768, tmp, nullptr, BTn, 768, 3072, 0);
    ln_res_kernel<<<BTn, 256, 0, stream>>>(tmp, h, hb, ln2_g + (size_t)d*768, ln2_b + (size_t)d*768);
  }

  float* logits = (float*)d_out;
  gemm_bf16_kernel<<<dim3(BTn/128, Vn/128), 256, 0, stream>>>(
      hb, wlT, bl, logits, nullptr, BTn, Vn, 768, 0);
  loss_row_kernel<<<BTn, 256, 0, stream>>>(logits, y, loss_rows);
  loss_reduce_kernel<<<1, 256, 0, stream>>>(loss_rows, logits + (size_t)BTn*Vn);
}

// Round 4
// 1741.194 us; speedup vs baseline: 1.0573x; 1.0573x over previous
//
#include <hip/hip_runtime.h>

#define Bn 4
#define Tn 1024
#define Cn 768
#define Hn 12
#define Dn 4
#define Vn 32000
#define BTn (Bn*Tn)

typedef __attribute__((ext_vector_type(8))) short short8;
typedef __attribute__((ext_vector_type(4))) float f32x4;

__device__ __forceinline__ unsigned short f2bf(float f) {
  union { float f; unsigned u; } v; v.f = f;
  unsigned r = v.u + 0x7fffu + ((v.u >> 16) & 1u);
  return (unsigned short)(r >> 16);
}

__device__ __forceinline__ void gload_lds16(const void* g, void* l) {
  __builtin_amdgcn_global_load_lds(
      (const __attribute__((address_space(1))) void*)g,
      (__attribute__((address_space(3))) void*)l, 16, 0, 0);
}

// ---------------- transpose fp32 [K][N] -> bf16 [N][K] ----------------
__global__ __launch_bounds__(256)
void transpose_bf16_kernel(const float* __restrict__ src, unsigned short* __restrict__ dst,
                           int K, int N) {
  __shared__ float tile[32][33];
  const int tx = threadIdx.x, ty = threadIdx.y;
  const int n0 = blockIdx.x * 32, k0 = blockIdx.y * 32;
#pragma unroll
  for (int i = 0; i < 4; ++i)
    tile[ty + i*8][tx] = src[(size_t)(k0 + ty + i*8) * N + n0 + tx];
  __syncthreads();
#pragma unroll
  for (int i = 0; i < 4; ++i)
    dst[(size_t)(n0 + ty + i*8) * K + k0 + tx] = f2bf(tile[tx][ty + i*8]);
}

// ---------------- embedding ----------------
__global__ __launch_bounds__(256)
void embed_kernel(const int* __restrict__ x, const float* __restrict__ wordemb,
                  const float* __restrict__ posemb, float* __restrict__ h,
                  unsigned short* __restrict__ hb) {
  int i4 = blockIdx.x * 256 + threadIdx.x;
  int row = i4 / (Cn/4), c4 = i4 % (Cn/4);
  int t = row & (Tn - 1);
  int tok = x[row];
  float4 a = ((const float4*)wordemb)[(size_t)tok * (Cn/4) + c4];
  float4 p = ((const float4*)posemb)[(size_t)t * (Cn/4) + c4];
  float4 s; s.x = a.x+p.x; s.y = a.y+p.y; s.z = a.z+p.z; s.w = a.w+p.w;
  ((float4*)h)[i4] = s;
  ushort4 u; u.x = f2bf(s.x); u.y = f2bf(s.y); u.z = f2bf(s.z); u.w = f2bf(s.w);
  ((ushort4*)hb)[i4] = u;
}

// ============ 256x256 pipelined bf16 MFMA GEMM (counted-vmcnt, 4-deep) ============
// 512 threads = 8 waves (2M x 4N), per-wave 128x64 output (8x4 16x16 frags).
// BK=32. LDS = 4 bufs x (A 256x32 + B 256x32) bf16 = 128 KB. 1 block/CU.
// Swizzle: physical 16B slot = s ^ ((row>>1)&3), pre-swizzled global src + swz read.
// Per iter: vmcnt(8) [2 tiles in flight], raw s_barrier, stage(t+3), 12 ds_read_b128,
//           setprio(1) 32 MFMA setprio(0).
__global__ __launch_bounds__(512, 2)
void gemm256_kernel(const unsigned short* __restrict__ A, const unsigned short* __restrict__ Bt,
                    const float* __restrict__ bias, float* __restrict__ Cf,
                    unsigned short* __restrict__ Cb, int M, int N, int K, int relu) {
  __shared__ unsigned short lds[4 * 16384];   // 128 KB
  const int t = threadIdx.x;
  const int by = blockIdx.x, bx = blockIdx.y;  // by = M-tile, bx = N-tile
  const int lane = t & 63, w = t >> 6;
  const int wr = w >> 2, wc = w & 3;           // 2 x 4 wave grid
  const int lr = lane & 15, lq = lane >> 4;
  const int xm = (lr >> 1) & 3;                // read-side slot XOR
  const int srow = lane >> 2;                  // staging: lane -> row-in-16-group
  const int sslot = (lane & 3) ^ ((lane >> 3) & 3);  // staging: pre-swizzled k-slot
  const int NT = K >> 5;

  f32x4 acc[8][4];
#pragma unroll
  for (int mi = 0; mi < 8; ++mi)
#pragma unroll
    for (int nj = 0; nj < 4; ++nj)
      acc[mi][nj] = (f32x4){0.f, 0.f, 0.f, 0.f};

  const unsigned short* aS = A  + (size_t)(by*256 + w*32 + srow) * K + sslot*8;
  const unsigned short* bS = Bt + (size_t)(bx*256 + w*32 + srow) * K + sslot*8;

  auto stage = [&](int tile) {
    const int bsel = tile & 3;
    unsigned short* ba = &lds[bsel*16384];
    unsigned short* bb = &lds[bsel*16384 + 8192];
    const int k0 = tile * 32;
    gload_lds16(aS + k0,                 &ba[(w*32)*32]);
    gload_lds16(aS + k0 + 16*(size_t)K,  &ba[(w*32 + 16)*32]);
    gload_lds16(bS + k0,                 &bb[(w*32)*32]);
    gload_lds16(bS + k0 + 16*(size_t)K,  &bb[(w*32 + 16)*32]);
  };

  auto compute = [&](int tile) {
    const int bsel = tile & 3;
    const unsigned short* ba = &lds[bsel*16384];
    const unsigned short* bb = &lds[bsel*16384 + 8192];
    short8 af[8], bfr[4];
#pragma unroll
    for (int nj = 0; nj < 4; ++nj)
      bfr[nj] = *(const short8*)&bb[(wc*64 + nj*16 + lr)*32 + (lq ^ xm)*8];
#pragma unroll
    for (int mi = 0; mi < 8; ++mi)
      af[mi] = *(const short8*)&ba[(wr*128 + mi*16 + lr)*32 + (lq ^ xm)*8];
    __builtin_amdgcn_s_setprio(1);
#pragma unroll
    for (int mi = 0; mi < 8; ++mi)
#pragma unroll
      for (int nj = 0; nj < 4; ++nj)
        acc[mi][nj] = __builtin_amdgcn_mfma_f32_16x16x32_bf16(af[mi], bfr[nj], acc[mi][nj], 0, 0, 0);
    __builtin_amdgcn_s_setprio(0);
  };

  stage(0); stage(1); stage(2);

  int tile = 0;
  for (; tile < NT - 2; ++tile) {
    asm volatile("s_waitcnt vmcnt(8)" ::: "memory");
    __builtin_amdgcn_s_barrier();
    __builtin_amdgcn_sched_barrier(0);
    if (tile + 3 < NT) stage(tile + 3);
    compute(tile);
  }
  asm volatile("s_waitcnt vmcnt(4)" ::: "memory");
  __builtin_amdgcn_s_barrier();
  __builtin_amdgcn_sched_barrier(0);
  compute(NT - 2);
  asm volatile("s_waitcnt vmcnt(0)" ::: "memory");
  __builtin_amdgcn_s_barrier();
  __builtin_amdgcn_sched_barrier(0);
  compute(NT - 1);

#pragma unroll
  for (int mi = 0; mi < 8; ++mi)
#pragma unroll
    for (int nj = 0; nj < 4; ++nj)
#pragma unroll
      for (int r = 0; r < 4; ++r) {
        int grow = by*256 + wr*128 + mi*16 + lq*4 + r;
        int gcol = bx*256 + wc*64 + nj*16 + lr;
        float v = acc[mi][nj][r];
        if (bias) v += bias[gcol];
        if (relu) v = fmaxf(v, 0.f);
        size_t idx = (size_t)grow * N + gcol;
        if (Cf) Cf[idx] = v;
        if (Cb) Cb[idx] = f2bf(v);
      }
}

// ---------------- 128x128 m97-style GEMM (kept for small-N: Wo, FF2) ----------------
__global__ __launch_bounds__(256)
void gemm_bf16_kernel(const unsigned short* __restrict__ A, const unsigned short* __restrict__ Bt,
                      const float* __restrict__ bias, float* __restrict__ Cf,
                      unsigned short* __restrict__ Cb, int M, int N, int K, int relu) {
  __shared__ unsigned short As[128*32];
  __shared__ unsigned short Bs[128*32];
  const int t = threadIdx.x;
  const int by = blockIdx.x, bx = blockIdx.y;
  const int lane = t & 63, w = t >> 6;
  const int wr = w >> 1, wc = w & 1;
  const int lr = lane & 15, lq = lane >> 4;

  f32x4 acc[4][4];
#pragma unroll
  for (int i = 0; i < 4; ++i)
#pragma unroll
    for (int j = 0; j < 4; ++j)
      acc[i][j] = (f32x4){0.f, 0.f, 0.f, 0.f};

  const int sl_row = lane >> 2;
  const int sl_col = (lane & 3) * 8;
  const unsigned short* agl = A  + (size_t)(by*128 + w*32 + sl_row) * K + sl_col;
  const unsigned short* bgl = Bt + (size_t)(bx*128 + w*32 + sl_row) * K + sl_col;
  unsigned short* asw = &As[(w*32)*32];
  unsigned short* bsw = &Bs[(w*32)*32];

  for (int k0 = 0; k0 < K; k0 += 32) {
    __syncthreads();
    gload_lds16(agl + k0,            asw);
    gload_lds16(agl + k0 + 16*(size_t)K, asw + 16*32);
    gload_lds16(bgl + k0,            bsw);
    gload_lds16(bgl + k0 + 16*(size_t)K, bsw + 16*32);
    __syncthreads();
    short8 af[4], bfr[4];
#pragma unroll
    for (int i = 0; i < 4; ++i) af[i]  = *(const short8*)&As[(wr*64 + i*16 + lr)*32 + lq*8];
#pragma unroll
    for (int j = 0; j < 4; ++j) bfr[j] = *(const short8*)&Bs[(wc*64 + j*16 + lr)*32 + lq*8];
#pragma unroll
    for (int i = 0; i < 4; ++i)
#pragma unroll
      for (int j = 0; j < 4; ++j)
        acc[i][j] = __builtin_amdgcn_mfma_f32_16x16x32_bf16(af[i], bfr[j], acc[i][j], 0, 0, 0);
  }

#pragma unroll
  for (int i = 0; i < 4; ++i)
#pragma unroll
    for (int j = 0; j < 4; ++j)
#pragma unroll
      for (int r = 0; r < 4; ++r) {
        int grow = by*128 + wr*64 + i*16 + lq*4 + r;
        int gcol = bx*128 + wc*64 + j*16 + lr;
        float v = acc[i][j][r];
        if (bias) v += bias[gcol];
        if (relu) v = fmaxf(v, 0.f);
        size_t idx = (size_t)grow * N + gcol;
        if (Cf) Cf[idx] = v;
        if (Cb) Cb[idx] = f2bf(v);
      }
}

// ---------------- vT: qkvb V-section [BT][2304] -> vT[b][h][d][t] (bf16) -------------
__global__ __launch_bounds__(256)
void vT_kernel(const unsigned short* __restrict__ qkvb, unsigned short* __restrict__ vT) {
  const int tb = blockIdx.x, hh = blockIdx.y, b = blockIdx.z;
  const int t = threadIdx.x;
  __shared__ unsigned short tile[64][65];
  const int r = t >> 2, c = t & 3;
  const unsigned short* src = qkvb + (size_t)(b*Tn + tb*64 + r) * 2304 + 1536 + hh*64 + c*16;
  short8 v0 = *(const short8*)src;
  short8 v1 = *(const short8*)(src + 8);
#pragma unroll
  for (int j = 0; j < 8; ++j) { tile[r][c*16 + j] = (unsigned short)v0[j]; tile[r][c*16 + 8 + j] = (unsigned short)v1[j]; }
  __syncthreads();
  unsigned short o[16];
#pragma unroll
  for (int j = 0; j < 16; ++j) o[j] = tile[c*16 + j][r];
  unsigned short* dst = vT + ((size_t)((b*Hn + hh)*64 + r)) * Tn + tb*64 + c*16;
  *(ushort4*)(dst)      = *(ushort4*)&o[0];
  *(ushort4*)(dst + 4)  = *(ushort4*)&o[4];
  *(ushort4*)(dst + 8)  = *(ushort4*)&o[8];
  *(ushort4*)(dst + 12) = *(ushort4*)&o[12];
}

// ---------------- MFMA flash attention: bf16 in/out, fp32 accum ----------------------
__global__ __launch_bounds__(256)
void attn_mfma_kernel(const unsigned short* __restrict__ qkvb,
                      const unsigned short* __restrict__ vT,
                      unsigned short* __restrict__ attb) {
  const int qb = blockIdx.x, hh = blockIdx.y, b = blockIdx.z;
  const int t = threadIdx.x;
  const int lane = t & 63, w = t >> 6;
  const int lr = lane & 15, lg = lane >> 4;
  const float scale = 0.03608439182435161f;   // 1/sqrt(768)

  __shared__ unsigned short Ks[64*64];
  __shared__ unsigned short Vs[64*64];
  __shared__ unsigned short Ps[4][16][72];

  const unsigned short* qsrc = qkvb + (size_t)(b*Tn + qb*64 + w*16 + lr)*2304 + hh*64 + lg*8;
  short8 qa0 = *(const short8*)(qsrc);
  short8 qa1 = *(const short8*)(qsrc + 32);

  f32x4 acc[4];
#pragma unroll
  for (int dt = 0; dt < 4; ++dt) acc[dt] = (f32x4){0.f,0.f,0.f,0.f};
  float m_run[4], l_run[4];
#pragma unroll
  for (int r = 0; r < 4; ++r) { m_run[r] = -1e30f; l_run[r] = 0.f; }

  const int sr = t >> 2, c2 = t & 3;

  for (int kvb = 0; kvb <= qb; ++kvb) {
    __syncthreads();
    {
      const unsigned short* ksrc = qkvb + (size_t)(b*Tn + kvb*64 + sr)*2304 + 768 + hh*64 + c2*16;
      short8 k0 = *(const short8*)ksrc;
      short8 k1 = *(const short8*)(ksrc + 8);
      const unsigned short* vsrc = vT + ((size_t)((b*Hn + hh)*64 + sr))*Tn + kvb*64 + c2*16;
      short8 vv0 = *(const short8*)vsrc;
      short8 vv1 = *(const short8*)(vsrc + 8);
      int s0 = (2*c2) ^ (sr & 7), s1 = (2*c2 + 1) ^ (sr & 7);
      *(short8*)&Ks[sr*64 + s0*8] = k0;
      *(short8*)&Ks[sr*64 + s1*8] = k1;
      *(short8*)&Vs[sr*64 + s0*8] = vv0;
      *(short8*)&Vs[sr*64 + s1*8] = vv1;
    }
    __syncthreads();

    f32x4 s[4];
#pragma unroll
    for (int kt = 0; kt < 4; ++kt) {
      int krow = kt*16 + lr;
      short8 kf0 = *(const short8*)&Ks[krow*64 + ((0 + lg) ^ (krow & 7))*8];
      short8 kf1 = *(const short8*)&Ks[krow*64 + ((4 + lg) ^ (krow & 7))*8];
      f32x4 a = (f32x4){0.f,0.f,0.f,0.f};
      a = __builtin_amdgcn_mfma_f32_16x16x32_bf16(qa0, kf0, a, 0, 0, 0);
      a = __builtin_amdgcn_mfma_f32_16x16x32_bf16(qa1, kf1, a, 0, 0, 0);
      s[kt] = a;
    }
    const bool diag = (kvb == qb);
#pragma unroll
    for (int kt = 0; kt < 4; ++kt)
#pragma unroll
      for (int r = 0; r < 4; ++r) {
        float v = s[kt][r] * scale;
        if (diag && (kt*16 + lr > w*16 + lg*4 + r)) v = -1e30f;
        s[kt][r] = v;
      }
#pragma unroll
    for (int r = 0; r < 4; ++r) {
      float m = fmaxf(fmaxf(s[0][r], s[1][r]), fmaxf(s[2][r], s[3][r]));
      m = fmaxf(m, __shfl_xor(m, 1));
      m = fmaxf(m, __shfl_xor(m, 2));
      m = fmaxf(m, __shfl_xor(m, 4));
      m = fmaxf(m, __shfl_xor(m, 8));
      float mn = fmaxf(m_run[r], m);
      float corr = __expf(m_run[r] - mn);
      m_run[r] = mn;
      float ps = 0.f;
#pragma unroll
      for (int kt = 0; kt < 4; ++kt) {
        float p = __expf(s[kt][r] - mn);
        s[kt][r] = p;
        ps += p;
      }
      ps += __shfl_xor(ps, 1);
      ps += __shfl_xor(ps, 2);
      ps += __shfl_xor(ps, 4);
      ps += __shfl_xor(ps, 8);
      l_run[r] = l_run[r] * corr + ps;
#pragma unroll
      for (int dt = 0; dt < 4; ++dt) acc[dt][r] *= corr;
    }
#pragma unroll
    for (int kt = 0; kt < 4; ++kt)
#pragma unroll
      for (int r = 0; r < 4; ++r)
        Ps[w][lg*4 + r][kt*16 + lr] = f2bf(s[kt][r]);
    short8 pa0 = *(const short8*)&Ps[w][lr][lg*8];
    short8 pa1 = *(const short8*)&Ps[w][lr][32 + lg*8];
#pragma unroll
    for (int dt = 0; dt < 4; ++dt) {
      int drow = dt*16 + lr;
      short8 vf0 = *(const short8*)&Vs[drow*64 + ((0 + lg) ^ (drow & 7))*8];
      short8 vf1 = *(const short8*)&Vs[drow*64 + ((4 + lg) ^ (drow & 7))*8];
      acc[dt] = __builtin_amdgcn_mfma_f32_16x16x32_bf16(pa0, vf0, acc[dt], 0, 0, 0);
      acc[dt] = __builtin_amdgcn_mfma_f32_16x16x32_bf16(pa1, vf1, acc[dt], 0, 0, 0);
    }
  }

  unsigned short* obase = attb + (size_t)(b*Tn + qb*64 + w*16)*768 + hh*64;
#pragma unroll
  for (int dt = 0; dt < 4; ++dt)
#pragma unroll
    for (int r = 0; r < 4; ++r) {
      float v = acc[dt][r] / l_run[r];
      obase[(size_t)(lg*4 + r)*768 + dt*16 + lr] = f2bf(v);
    }
}

// ---------------- residual + layernorm ----------------
__global__ __launch_bounds__(256)
void ln_res_kernel(const float* __restrict__ x, float* __restrict__ h,
                   unsigned short* __restrict__ hb, const float* __restrict__ g,
                   const float* __restrict__ bb) {
  const int row = blockIdx.x, tid = threadIdx.x;
  const float* xr = x + (size_t)row * Cn;
  float v[3], s1 = 0.f, s2 = 0.f;
#pragma unroll
  for (int j = 0; j < 3; ++j) { v[j] = xr[tid + j*256]; s1 += v[j]; s2 += v[j]*v[j]; }
  __shared__ float r1[256], r2[256];
  r1[tid] = s1; r2[tid] = s2;
  __syncthreads();
  for (int s = 128; s > 0; s >>= 1) {
    if (tid < s) { r1[tid] += r1[tid+s]; r2[tid] += r2[tid+s]; }
    __syncthreads();
  }
  float mu = r1[0] * (1.f/768.f);
  float var = r2[0] * (1.f/768.f) - mu*mu;
  float rs = rsqrtf(var + 1e-5f);
  float* hr = h + (size_t)row * Cn;
  unsigned short* hbr = hb + (size_t)row * Cn;
#pragma unroll
  for (int j = 0; j < 3; ++j) {
    int c = tid + j*256;
    float y = hr[c] + (v[j]-mu)*rs*g[c] + bb[c];
    hr[c] = y;
    hbr[c] = f2bf(y);
  }
}

// ---------------- loss ----------------
__global__ __launch_bounds__(256)
void loss_row_kernel(const float* __restrict__ logits, const int* __restrict__ y,
                     float* __restrict__ loss_rows) {
  const int row = blockIdx.x, tid = threadIdx.x;
  const float* lg = logits + (size_t)row * Vn;
  __shared__ float red[256];
  float mx = -1e30f;
  for (int j = 0; j < Vn/256; ++j) mx = fmaxf(mx, lg[tid + j*256]);
  red[tid] = mx; __syncthreads();
  for (int s = 128; s > 0; s >>= 1) {
    if (tid < s) red[tid] = fmaxf(red[tid], red[tid+s]);
    __syncthreads();
  }
  mx = red[0]; __syncthreads();
  float sum = 0.f;
  for (int j = 0; j < Vn/256; ++j) sum += __expf(lg[tid + j*256] - mx);
  red[tid] = sum; __syncthreads();
  for (int s = 128; s > 0; s >>= 1) {
    if (tid < s) red[tid] += red[tid+s];
    __syncthreads();
  }
  if (tid == 0) {
    float lse = mx + __logf(red[0]);
    loss_rows[row] = lse - lg[y[row]];
  }
}

__global__ __launch_bounds__(256)
void loss_reduce_kernel(const float* __restrict__ loss_rows, float* __restrict__ out) {
  const int tid = threadIdx.x;
  float s = 0.f;
  for (int j = 0; j < BTn/256; ++j) s += loss_rows[tid + j*256];
  __shared__ float red[256];
  red[tid] = s; __syncthreads();
  for (int st = 128; st > 0; st >>= 1) {
    if (tid < st) red[tid] += red[tid+st];
    __syncthreads();
  }
  if (tid == 0) out[0] = red[0] * (1.f/(float)BTn);
}

// =====================================================================================
extern "C" void kernel_launch(void* const* d_in, const int* in_sizes, int n_in,
                              void* d_out, int out_size, void* d_ws, size_t ws_size,
                              hipStream_t stream) {
  const int*   x       = (const int*)  d_in[0];
  const int*   y       = (const int*)  d_in[1];
  const float* wordemb = (const float*)d_in[2];
  const float* posemb  = (const float*)d_in[3];
  const float* Wq      = (const float*)d_in[4];
  const float* Wk      = (const float*)d_in[5];
  const float* Wv      = (const float*)d_in[6];
  const float* Wo      = (const float*)d_in[7];
  const float* bo      = (const float*)d_in[8];
  const float* ln1_g   = (const float*)d_in[9];
  const float* ln1_b   = (const float*)d_in[10];
  const float* W1      = (const float*)d_in[11];
  const float* b1      = (const float*)d_in[12];
  const float* W2      = (const float*)d_in[13];
  const float* b2      = (const float*)d_in[14];
  const float* ln2_g   = (const float*)d_in[15];
  const float* ln2_b   = (const float*)d_in[16];
  const float* Wl      = (const float*)d_in[17];
  const float* bl      = (const float*)d_in[18];

  char* ws = (char*)d_ws;
  size_t off = 0;
  auto alloc = [&](size_t bytes) -> char* {
    char* p = ws + off;
    off += (bytes + 255) & ~(size_t)255;
    return p;
  };
  unsigned short* wqkvT = (unsigned short*)alloc((size_t)Dn*2304*768*2);
  unsigned short* woT   = (unsigned short*)alloc((size_t)Dn*768*768*2);
  unsigned short* w1T   = (unsigned short*)alloc((size_t)Dn*3072*768*2);
  unsigned short* w2T   = (unsigned short*)alloc((size_t)Dn*768*3072*2);
  unsigned short* wlT   = (unsigned short*)alloc((size_t)Vn*768*2);
  float*          h     = (float*)alloc((size_t)BTn*Cn*4);
  unsigned short* hb    = (unsigned short*)alloc((size_t)BTn*Cn*2);
  unsigned short* qkvb  = (unsigned short*)alloc((size_t)BTn*3072*2);
  unsigned short* vTb   = (unsigned short*)alloc((size_t)Bn*Hn*64*Tn*2);
  unsigned short* attb  = (unsigned short*)alloc((size_t)BTn*Cn*2);
  float*          tmp   = (float*)alloc((size_t)BTn*Cn*4);
  float*          loss_rows = (float*)alloc((size_t)BTn*4);
  unsigned short* ff1b  = qkvb;  // alias: qkv dead once attn done

  dim3 tb(32, 8);
  for (int d = 0; d < Dn; ++d) {
    transpose_bf16_kernel<<<dim3(24,24), tb, 0, stream>>>(Wq + (size_t)d*Cn*Cn, wqkvT + (size_t)d*2304*768,            Cn, Cn);
    transpose_bf16_kernel<<<dim3(24,24), tb, 0, stream>>>(Wk + (size_t)d*Cn*Cn, wqkvT + (size_t)d*2304*768 + 768*768,  Cn, Cn);
    transpose_bf16_kernel<<<dim3(24,24), tb, 0, stream>>>(Wv + (size_t)d*Cn*Cn, wqkvT + (size_t)d*2304*768 + 1536*768, Cn, Cn);
    transpose_bf16_kernel<<<dim3(24,24), tb, 0, stream>>>(Wo + (size_t)d*Cn*Cn, woT + (size_t)d*768*768,  Cn, Cn);
    transpose_bf16_kernel<<<dim3(96,24), tb, 0, stream>>>(W1 + (size_t)d*768*3072, w1T + (size_t)d*3072*768, 768, 3072);
    transpose_bf16_kernel<<<dim3(24,96), tb, 0, stream>>>(W2 + (size_t)d*3072*768, w2T + (size_t)d*768*3072, 3072, 768);
  }
  transpose_bf16_kernel<<<dim3(1000,24), tb, 0, stream>>>(Wl, wlT, 768, Vn);

  embed_kernel<<<(BTn*Cn/4)/256, 256, 0, stream>>>(x, wordemb, posemb, h, hb);

  for (int d = 0; d < Dn; ++d) {
    gemm256_kernel<<<dim3(BTn/256, 2304/256), 512, 0, stream>>>(
        hb, wqkvT + (size_t)d*2304*768, nullptr, nullptr, qkvb, BTn, 2304, 768, 0);
    vT_kernel<<<dim3(Tn/64, Hn, Bn), 256, 0, stream>>>(qkvb, vTb);
    attn_mfma_kernel<<<dim3(Tn/64, Hn, Bn), 256, 0, stream>>>(qkvb, vTb, attb);
    gemm_bf16_kernel<<<dim3(BTn/128, 768/128), 256, 0, stream>>>(
        attb, woT + (size_t)d*768*768, bo + (size_t)d*768, tmp, nullptr, BTn, 768, 768, 0);
    ln_res_kernel<<<BTn, 256, 0, stream>>>(tmp, h, hb, ln1_g + (size_t)d*768, ln1_b + (size_t)d*768);
    gemm256_kernel<<<dim3(BTn/256, 3072/256), 512, 0, stream>>>(
        hb, w1T + (size_t)d*3072*768, b1 + (size_t)d*3072, nullptr, ff1b, BTn, 3072, 768, 1);
    gemm_bf16_kernel<<<dim3(BTn/128, 768/128), 256, 0, stream>>>(
        ff1b, w2T + (size_t)d*768*3072, b2 + (size_t)d*768, tmp, nullptr, BTn, 768, 3072, 0);
    ln_res_kernel<<<BTn, 256, 0, stream>>>(tmp, h, hb, ln2_g + (size_t)d*768, ln2_b + (size_t)d*768);
  }

  float* logits = (float*)d_out;
  gemm256_kernel<<<dim3(BTn/256, Vn/256), 512, 0, stream>>>(
      hb, wlT, bl, logits, nullptr, BTn, Vn, 768, 0);
  loss_row_kernel<<<BTn, 256, 0, stream>>>(logits, y, loss_rows);
  loss_reduce_kernel<<<1, 256, 0, stream>>>(loss_rows, logits + (size_t)BTn*Vn);
}

// Round 6
// 1504.408 us; speedup vs baseline: 1.2237x; 1.1574x over previous
//
#include <hip/hip_runtime.h>

#define Bn 4
#define Tn 1024
#define Cn 768
#define Hn 12
#define Dn 4
#define Vn 32000
#define BTn (Bn*Tn)

typedef __attribute__((ext_vector_type(8))) short short8;
typedef __attribute__((ext_vector_type(4))) float f32x4;

__device__ __forceinline__ unsigned short f2bf(float f) {
  union { float f; unsigned u; } v; v.f = f;
  unsigned r = v.u + 0x7fffu + ((v.u >> 16) & 1u);
  return (unsigned short)(r >> 16);
}

__device__ __forceinline__ void gload_lds16(const void* g, void* l) {
  __builtin_amdgcn_global_load_lds(
      (const __attribute__((address_space(1))) void*)g,
      (__attribute__((address_space(3))) void*)l, 16, 0, 0);
}

// ---------------- transpose fp32 [K][N] -> bf16 [N][K] ----------------
__global__ __launch_bounds__(256)
void transpose_bf16_kernel(const float* __restrict__ src, unsigned short* __restrict__ dst,
                           int K, int N) {
  __shared__ float tile[32][33];
  const int tx = threadIdx.x, ty = threadIdx.y;
  const int n0 = blockIdx.x * 32, k0 = blockIdx.y * 32;
#pragma unroll
  for (int i = 0; i < 4; ++i)
    tile[ty + i*8][tx] = src[(size_t)(k0 + ty + i*8) * N + n0 + tx];
  __syncthreads();
#pragma unroll
  for (int i = 0; i < 4; ++i)
    dst[(size_t)(n0 + ty + i*8) * K + k0 + tx] = f2bf(tile[tx][ty + i*8]);
}

// ---------------- embedding ----------------
__global__ __launch_bounds__(256)
void embed_kernel(const int* __restrict__ x, const float* __restrict__ wordemb,
                  const float* __restrict__ posemb, float* __restrict__ h,
                  unsigned short* __restrict__ hb) {
  int i4 = blockIdx.x * 256 + threadIdx.x;
  int row = i4 / (Cn/4), c4 = i4 % (Cn/4);
  int t = row & (Tn - 1);
  int tok = x[row];
  float4 a = ((const float4*)wordemb)[(size_t)tok * (Cn/4) + c4];
  float4 p = ((const float4*)posemb)[(size_t)t * (Cn/4) + c4];
  float4 s; s.x = a.x+p.x; s.y = a.y+p.y; s.z = a.z+p.z; s.w = a.w+p.w;
  ((float4*)h)[i4] = s;
  ushort4 u; u.x = f2bf(s.x); u.y = f2bf(s.y); u.z = f2bf(s.z); u.w = f2bf(s.w);
  ((ushort4*)hb)[i4] = u;
}

// ============ pipelined bf16 MFMA GEMM, frag-prefetch, audited vmcnt ledger ============
// Phase p body: vmcnt(4) [retires S(p+1); outstanding {S(p+1),S(p+2)}=8] -> barrier ->
//   STAGE(p+3) [buffer (p+3)&3 last consumed by cluster(p-1), which precedes barrier(p)
//   in every wave's program order -> overwrite safe] -> prefetch frags(p+1) -> MFMA(p).
// Tail: loop ends at phase NT-3 (ledger still exact); epilogue phase NT-2 uses vmcnt(0)
// (only S(NT-1) outstanding), phase NT-1 is pure MFMA. NT even, >= 4.
// PFA: prefetch A-frags too (small tiles); else A read in-phase (saves ~64 VGPR).
template<int WM, int WN, int MI, int NJ, bool PFA>
__global__ __launch_bounds__(WM*WN*64, 2)
void gemm_pipe(const unsigned short* __restrict__ A, const unsigned short* __restrict__ Bt,
               const float* __restrict__ bias, float* __restrict__ Cf,
               unsigned short* __restrict__ Cb, int M, int N, int K, int relu) {
  constexpr int BM = WM*MI*16, BN = WN*NJ*16, ROWS = BM + BN;
  __shared__ unsigned short lds[4*ROWS*32];
  const int t = threadIdx.x;
  const int by = blockIdx.x, bx = blockIdx.y;
  const int lane = t & 63, w = t >> 6;
  const int wr = w / WN, wc = w % WN;
  const int lr = lane & 15, lq = lane >> 4;
  const int xm = (lr >> 1) & 3;
  const int srow = lane >> 2, sslot = (lane & 3) ^ ((lane >> 3) & 3);
  const int NT = K >> 5;

  f32x4 acc[MI][NJ];
#pragma unroll
  for (int mi = 0; mi < MI; ++mi)
#pragma unroll
    for (int nj = 0; nj < NJ; ++nj)
      acc[mi][nj] = (f32x4){0.f, 0.f, 0.f, 0.f};

  const unsigned short* aS = A  + (size_t)(by*BM + w*32 + srow)*K + sslot*8;
  const unsigned short* bS = Bt + (size_t)(bx*BN + w*32 + srow)*K + sslot*8;

  auto STAGE = [&](int tile) {
    unsigned short* ba = &lds[(tile & 3)*ROWS*32];
    unsigned short* bb = ba + BM*32;
    const int k0 = tile*32;
    gload_lds16(aS + k0,                 &ba[(w*32)*32]);
    gload_lds16(aS + k0 + 16*(size_t)K,  &ba[(w*32+16)*32]);
    gload_lds16(bS + k0,                 &bb[(w*32)*32]);
    gload_lds16(bS + k0 + 16*(size_t)K,  &bb[(w*32+16)*32]);
  };
  auto RDA = [&](int tile, short8* af) {
    const unsigned short* ba = &lds[(tile & 3)*ROWS*32];
#pragma unroll
    for (int mi = 0; mi < MI; ++mi)
      af[mi] = *(const short8*)&ba[(wr*MI*16 + mi*16 + lr)*32 + (lq ^ xm)*8];
  };
  auto RDB = [&](int tile, short8* bf) {
    const unsigned short* bb = &lds[(tile & 3)*ROWS*32 + BM*32];
#pragma unroll
    for (int nj = 0; nj < NJ; ++nj)
      bf[nj] = *(const short8*)&bb[(wc*NJ*16 + nj*16 + lr)*32 + (lq ^ xm)*8];
  };
  auto CL = [&](const short8* af, const short8* bf) {
    __builtin_amdgcn_s_setprio(1);
#pragma unroll
    for (int mi = 0; mi < MI; ++mi)
#pragma unroll
      for (int nj = 0; nj < NJ; ++nj)
        acc[mi][nj] = __builtin_amdgcn_mfma_f32_16x16x32_bf16(af[mi], bf[nj], acc[mi][nj], 0, 0, 0);
    __builtin_amdgcn_s_setprio(0);
  };

  short8 afA[MI], afB[MI], bfA[NJ], bfB[NJ];

  STAGE(0); STAGE(1); STAGE(2);
  asm volatile("s_waitcnt vmcnt(8)" ::: "memory");   // 12 out -> retire S0
  __builtin_amdgcn_s_barrier();
  __builtin_amdgcn_sched_barrier(0);
  if (PFA) RDA(0, afA);
  RDB(0, bfA);

  for (int tt = 0; tt + 2 < NT; tt += 2) {
    // phase tt (even): cluster tile tt, prefetch tile tt+1
    asm volatile("s_waitcnt vmcnt(4)" ::: "memory");
    __builtin_amdgcn_s_barrier();
    __builtin_amdgcn_sched_barrier(0);
    STAGE(tt + 3);                       // tt+3 <= NT-1 in loop range
    if (PFA) { RDA(tt + 1, afB); RDB(tt + 1, bfB); }
    else     { RDA(tt, afA);     RDB(tt + 1, bfB); }
    CL(afA, bfA);

    // phase tt+1 (odd): cluster tile tt+1, prefetch tile tt+2
    asm volatile("s_waitcnt vmcnt(4)" ::: "memory");
    __builtin_amdgcn_s_barrier();
    __builtin_amdgcn_sched_barrier(0);
    if (tt + 4 < NT) STAGE(tt + 4);
    if (PFA) { RDA(tt + 2, afA); RDB(tt + 2, bfA); }
    else     { RDA(tt + 1, afA); RDB(tt + 2, bfA); }
    CL(PFA ? (const short8*)afB : (const short8*)afA, bfB);
  }

  // epilogue: phases NT-2, NT-1 (only S(NT-1) outstanding -> vmcnt(0))
  asm volatile("s_waitcnt vmcnt(0)" ::: "memory");
  __builtin_amdgcn_s_barrier();
  __builtin_amdgcn_sched_barrier(0);
  if (PFA) {
    RDA(NT - 1, afB); RDB(NT - 1, bfB);
    CL(afA, bfA);
    CL(afB, bfB);
  } else {
    RDA(NT - 2, afA); RDB(NT - 1, bfB);
    CL(afA, bfA);
    RDA(NT - 1, afA);
    CL(afA, bfB);
  }

#pragma unroll
  for (int mi = 0; mi < MI; ++mi)
#pragma unroll
    for (int nj = 0; nj < NJ; ++nj)
#pragma unroll
      for (int r = 0; r < 4; ++r) {
        int grow = by*BM + wr*MI*16 + mi*16 + lq*4 + r;
        int gcol = bx*BN + wc*NJ*16 + nj*16 + lr;
        float v = acc[mi][nj][r];
        if (bias) v += bias[gcol];
        if (relu) v = fmaxf(v, 0.f);
        size_t idx = (size_t)grow * N + gcol;
        if (Cf) Cf[idx] = v;
        if (Cb) Cb[idx] = f2bf(v);
      }
}

// ---------------- vT: qkvb V-section [BT][2304] -> vT[b][h][d][t] (bf16) -------------
__global__ __launch_bounds__(256)
void vT_kernel(const unsigned short* __restrict__ qkvb, unsigned short* __restrict__ vT) {
  const int tb = blockIdx.x, hh = blockIdx.y, b = blockIdx.z;
  const int t = threadIdx.x;
  __shared__ unsigned short tile[64][65];
  const int r = t >> 2, c = t & 3;
  const unsigned short* src = qkvb + (size_t)(b*Tn + tb*64 + r) * 2304 + 1536 + hh*64 + c*16;
  short8 v0 = *(const short8*)src;
  short8 v1 = *(const short8*)(src + 8);
#pragma unroll
  for (int j = 0; j < 8; ++j) { tile[r][c*16 + j] = (unsigned short)v0[j]; tile[r][c*16 + 8 + j] = (unsigned short)v1[j]; }
  __syncthreads();
  unsigned short o[16];
#pragma unroll
  for (int j = 0; j < 16; ++j) o[j] = tile[c*16 + j][r];
  unsigned short* dst = vT + ((size_t)((b*Hn + hh)*64 + r)) * Tn + tb*64 + c*16;
  *(ushort4*)(dst)      = *(ushort4*)&o[0];
  *(ushort4*)(dst + 4)  = *(ushort4*)&o[4];
  *(ushort4*)(dst + 8)  = *(ushort4*)&o[8];
  *(ushort4*)(dst + 12) = *(ushort4*)&o[12];
}

// ---------------- MFMA flash attention: bf16 in/out, fp32 accum ----------------------
__global__ __launch_bounds__(256)
void attn_mfma_kernel(const unsigned short* __restrict__ qkvb,
                      const unsigned short* __restrict__ vT,
                      unsigned short* __restrict__ attb) {
  const int qb = blockIdx.x, hh = blockIdx.y, b = blockIdx.z;
  const int t = threadIdx.x;
  const int lane = t & 63, w = t >> 6;
  const int lr = lane & 15, lg = lane >> 4;
  const float scale = 0.03608439182435161f;   // 1/sqrt(768)

  __shared__ unsigned short Ks[64*64];
  __shared__ unsigned short Vs[64*64];
  __shared__ unsigned short Ps[4][16][72];

  const unsigned short* qsrc = qkvb + (size_t)(b*Tn + qb*64 + w*16 + lr)*2304 + hh*64 + lg*8;
  short8 qa0 = *(const short8*)(qsrc);
  short8 qa1 = *(const short8*)(qsrc + 32);

  f32x4 acc[4];
#pragma unroll
  for (int dt = 0; dt < 4; ++dt) acc[dt] = (f32x4){0.f,0.f,0.f,0.f};
  float m_run[4], l_run[4];
#pragma unroll
  for (int r = 0; r < 4; ++r) { m_run[r] = -1e30f; l_run[r] = 0.f; }

  const int sr = t >> 2, c2 = t & 3;

  for (int kvb = 0; kvb <= qb; ++kvb) {
    __syncthreads();
    {
      const unsigned short* ksrc = qkvb + (size_t)(b*Tn + kvb*64 + sr)*2304 + 768 + hh*64 + c2*16;
      short8 k0 = *(const short8*)ksrc;
      short8 k1 = *(const short8*)(ksrc + 8);
      const unsigned short* vsrc = vT + ((size_t)((b*Hn + hh)*64 + sr))*Tn + kvb*64 + c2*16;
      short8 vv0 = *(const short8*)vsrc;
      short8 vv1 = *(const short8*)(vsrc + 8);
      int s0 = (2*c2) ^ (sr & 7), s1 = (2*c2 + 1) ^ (sr & 7);
      *(short8*)&Ks[sr*64 + s0*8] = k0;
      *(short8*)&Ks[sr*64 + s1*8] = k1;
      *(short8*)&Vs[sr*64 + s0*8] = vv0;
      *(short8*)&Vs[sr*64 + s1*8] = vv1;
    }
    __syncthreads();

    f32x4 s[4];
#pragma unroll
    for (int kt = 0; kt < 4; ++kt) {
      int krow = kt*16 + lr;
      short8 kf0 = *(const short8*)&Ks[krow*64 + ((0 + lg) ^ (krow & 7))*8];
      short8 kf1 = *(const short8*)&Ks[krow*64 + ((4 + lg) ^ (krow & 7))*8];
      f32x4 a = (f32x4){0.f,0.f,0.f,0.f};
      a = __builtin_amdgcn_mfma_f32_16x16x32_bf16(qa0, kf0, a, 0, 0, 0);
      a = __builtin_amdgcn_mfma_f32_16x16x32_bf16(qa1, kf1, a, 0, 0, 0);
      s[kt] = a;
    }
    const bool diag = (kvb == qb);
#pragma unroll
    for (int kt = 0; kt < 4; ++kt)
#pragma unroll
      for (int r = 0; r < 4; ++r) {
        float v = s[kt][r] * scale;
        if (diag && (kt*16 + lr > w*16 + lg*4 + r)) v = -1e30f;
        s[kt][r] = v;
      }
#pragma unroll
    for (int r = 0; r < 4; ++r) {
      float m = fmaxf(fmaxf(s[0][r], s[1][r]), fmaxf(s[2][r], s[3][r]));
      m = fmaxf(m, __shfl_xor(m, 1));
      m = fmaxf(m, __shfl_xor(m, 2));
      m = fmaxf(m, __shfl_xor(m, 4));
      m = fmaxf(m, __shfl_xor(m, 8));
      float mn = fmaxf(m_run[r], m);
      float corr = __expf(m_run[r] - mn);
      m_run[r] = mn;
      float ps = 0.f;
#pragma unroll
      for (int kt = 0; kt < 4; ++kt) {
        float p = __expf(s[kt][r] - mn);
        s[kt][r] = p;
        ps += p;
      }
      ps += __shfl_xor(ps, 1);
      ps += __shfl_xor(ps, 2);
      ps += __shfl_xor(ps, 4);
      ps += __shfl_xor(ps, 8);
      l_run[r] = l_run[r] * corr + ps;
#pragma unroll
      for (int dt = 0; dt < 4; ++dt) acc[dt][r] *= corr;
    }
#pragma unroll
    for (int kt = 0; kt < 4; ++kt)
#pragma unroll
      for (int r = 0; r < 4; ++r)
        Ps[w][lg*4 + r][kt*16 + lr] = f2bf(s[kt][r]);
    short8 pa0 = *(const short8*)&Ps[w][lr][lg*8];
    short8 pa1 = *(const short8*)&Ps[w][lr][32 + lg*8];
#pragma unroll
    for (int dt = 0; dt < 4; ++dt) {
      int drow = dt*16 + lr;
      short8 vf0 = *(const short8*)&Vs[drow*64 + ((0 + lg) ^ (drow & 7))*8];
      short8 vf1 = *(const short8*)&Vs[drow*64 + ((4 + lg) ^ (drow & 7))*8];
      acc[dt] = __builtin_amdgcn_mfma_f32_16x16x32_bf16(pa0, vf0, acc[dt], 0, 0, 0);
      acc[dt] = __builtin_amdgcn_mfma_f32_16x16x32_bf16(pa1, vf1, acc[dt], 0, 0, 0);
    }
  }

  unsigned short* obase = attb + (size_t)(b*Tn + qb*64 + w*16)*768 + hh*64;
#pragma unroll
  for (int dt = 0; dt < 4; ++dt)
#pragma unroll
    for (int r = 0; r < 4; ++r) {
      float v = acc[dt][r] / l_run[r];
      obase[(size_t)(lg*4 + r)*768 + dt*16 + lr] = f2bf(v);
    }
}

// ---------------- residual + layernorm ----------------
__global__ __launch_bounds__(256)
void ln_res_kernel(const float* __restrict__ x, float* __restrict__ h,
                   unsigned short* __restrict__ hb, const float* __restrict__ g,
                   const float* __restrict__ bb) {
  const int row = blockIdx.x, tid = threadIdx.x;
  const float* xr = x + (size_t)row * Cn;
  float v[3], s1 = 0.f, s2 = 0.f;
#pragma unroll
  for (int j = 0; j < 3; ++j) { v[j] = xr[tid + j*256]; s1 += v[j]; s2 += v[j]*v[j]; }
  __shared__ float r1[256], r2[256];
  r1[tid] = s1; r2[tid] = s2;
  __syncthreads();
  for (int s = 128; s > 0; s >>= 1) {
    if (tid < s) { r1[tid] += r1[tid+s]; r2[tid] += r2[tid+s]; }
    __syncthreads();
  }
  float mu = r1[0] * (1.f/768.f);
  float var = r2[0] * (1.f/768.f) - mu*mu;
  float rs = rsqrtf(var + 1e-5f);
  float* hr = h + (size_t)row * Cn;
  unsigned short* hbr = hb + (size_t)row * Cn;
#pragma unroll
  for (int j = 0; j < 3; ++j) {
    int c = tid + j*256;
    float y = hr[c] + (v[j]-mu)*rs*g[c] + bb[c];
    hr[c] = y;
    hbr[c] = f2bf(y);
  }
}

// ---------------- loss: single-pass online LSE per row ----------------
__global__ __launch_bounds__(256)
void loss_row_kernel(const float* __restrict__ logits, const int* __restrict__ y,
                     float* __restrict__ loss_rows) {
  const int row = blockIdx.x, tid = threadIdx.x;
  const float* lg = logits + (size_t)row * Vn;
  float m = -1e30f, s = 0.f;
  for (int j = 0; j < Vn/256; ++j) {
    float v = lg[tid + j*256];
    float mn = fmaxf(m, v);
    s = s * __expf(m - mn) + __expf(v - mn);
    m = mn;
  }
  __shared__ float rm[256], rs_[256];
  rm[tid] = m; rs_[tid] = s;
  __syncthreads();
  for (int st = 128; st > 0; st >>= 1) {
    if (tid < st) {
      float m2 = rm[tid+st], s2 = rs_[tid+st];
      float mn = fmaxf(rm[tid], m2);
      rs_[tid] = rs_[tid]*__expf(rm[tid]-mn) + s2*__expf(m2-mn);
      rm[tid] = mn;
    }
    __syncthreads();
  }
  if (tid == 0) loss_rows[row] = rm[0] + __logf(rs_[0]) - lg[y[row]];
}

__global__ __launch_bounds__(256)
void loss_reduce_kernel(const float* __restrict__ loss_rows, float* __restrict__ out) {
  const int tid = threadIdx.x;
  float s = 0.f;
  for (int j = 0; j < BTn/256; ++j) s += loss_rows[tid + j*256];
  __shared__ float red[256];
  red[tid] = s; __syncthreads();
  for (int st = 128; st > 0; st >>= 1) {
    if (tid < st) red[tid] += red[tid+st];
    __syncthreads();
  }
  if (tid == 0) out[0] = red[0] * (1.f/(float)BTn);
}

// =====================================================================================
extern "C" void kernel_launch(void* const* d_in, const int* in_sizes, int n_in,
                              void* d_out, int out_size, void* d_ws, size_t ws_size,
                              hipStream_t stream) {
  const int*   x       = (const int*)  d_in[0];
  const int*   y       = (const int*)  d_in[1];
  const float* wordemb = (const float*)d_in[2];
  const float* posemb  = (const float*)d_in[3];
  const float* Wq      = (const float*)d_in[4];
  const float* Wk      = (const float*)d_in[5];
  const float* Wv      = (const float*)d_in[6];
  const float* Wo      = (const float*)d_in[7];
  const float* bo      = (const float*)d_in[8];
  const float* ln1_g   = (const float*)d_in[9];
  const float* ln1_b   = (const float*)d_in[10];
  const float* W1      = (const float*)d_in[11];
  const float* b1      = (const float*)d_in[12];
  const float* W2      = (const float*)d_in[13];
  const float* b2      = (const float*)d_in[14];
  const float* ln2_g   = (const float*)d_in[15];
  const float* ln2_b   = (const float*)d_in[16];
  const float* Wl      = (const float*)d_in[17];
  const float* bl      = (const float*)d_in[18];

  char* ws = (char*)d_ws;
  size_t off = 0;
  auto alloc = [&](size_t bytes) -> char* {
    char* p = ws + off;
    off += (bytes + 255) & ~(size_t)255;
    return p;
  };
  unsigned short* wqkvT = (unsigned short*)alloc((size_t)Dn*2304*768*2);
  unsigned short* woT   = (unsigned short*)alloc((size_t)Dn*768*768*2);
  unsigned short* w1T   = (unsigned short*)alloc((size_t)Dn*3072*768*2);
  unsigned short* w2T   = (unsigned short*)alloc((size_t)Dn*768*3072*2);
  unsigned short* wlT   = (unsigned short*)alloc((size_t)Vn*768*2);
  float*          h     = (float*)alloc((size_t)BTn*Cn*4);
  unsigned short* hb    = (unsigned short*)alloc((size_t)BTn*Cn*2);
  unsigned short* qkvb  = (unsigned short*)alloc((size_t)BTn*3072*2);
  unsigned short* vTb   = (unsigned short*)alloc((size_t)Bn*Hn*64*Tn*2);
  unsigned short* attb  = (unsigned short*)alloc((size_t)BTn*Cn*2);
  float*          tmp   = (float*)alloc((size_t)BTn*Cn*4);
  float*          loss_rows = (float*)alloc((size_t)BTn*4);
  unsigned short* ff1b  = qkvb;  // alias: qkv dead once attn done

  dim3 tb(32, 8);
  for (int d = 0; d < Dn; ++d) {
    transpose_bf16_kernel<<<dim3(24,24), tb, 0, stream>>>(Wq + (size_t)d*Cn*Cn, wqkvT + (size_t)d*2304*768,            Cn, Cn);
    transpose_bf16_kernel<<<dim3(24,24), tb, 0, stream>>>(Wk + (size_t)d*Cn*Cn, wqkvT + (size_t)d*2304*768 + 768*768,  Cn, Cn);
    transpose_bf16_kernel<<<dim3(24,24), tb, 0, stream>>>(Wv + (size_t)d*Cn*Cn, wqkvT + (size_t)d*2304*768 + 1536*768, Cn, Cn);
    transpose_bf16_kernel<<<dim3(24,24), tb, 0, stream>>>(Wo + (size_t)d*Cn*Cn, woT + (size_t)d*768*768,  Cn, Cn);
    transpose_bf16_kernel<<<dim3(96,24), tb, 0, stream>>>(W1 + (size_t)d*768*3072, w1T + (size_t)d*3072*768, 768, 3072);
    transpose_bf16_kernel<<<dim3(24,96), tb, 0, stream>>>(W2 + (size_t)d*3072*768, w2T + (size_t)d*768*3072, 3072, 768);
  }
  transpose_bf16_kernel<<<dim3(1000,24), tb, 0, stream>>>(Wl, wlT, 768, Vn);

  embed_kernel<<<(BTn*Cn/4)/256, 256, 0, stream>>>(x, wordemb, posemb, h, hb);

  for (int d = 0; d < Dn; ++d) {
    gemm_pipe<2,2,4,4,true><<<dim3(BTn/128, 2304/128), 256, 0, stream>>>(
        hb, wqkvT + (size_t)d*2304*768, nullptr, nullptr, qkvb, BTn, 2304, 768, 0);
    vT_kernel<<<dim3(Tn/64, Hn, Bn), 256, 0, stream>>>(qkvb, vTb);
    attn_mfma_kernel<<<dim3(Tn/64, Hn, Bn), 256, 0, stream>>>(qkvb, vTb, attb);
    gemm_pipe<2,2,4,4,true><<<dim3(BTn/128, 768/128), 256, 0, stream>>>(
        attb, woT + (size_t)d*768*768, bo + (size_t)d*768, tmp, nullptr, BTn, 768, 768, 0);
    ln_res_kernel<<<BTn, 256, 0, stream>>>(tmp, h, hb, ln1_g + (size_t)d*768, ln1_b + (size_t)d*768);
    gemm_pipe<2,2,4,4,true><<<dim3(BTn/128, 3072/128), 256, 0, stream>>>(
        hb, w1T + (size_t)d*3072*768, b1 + (size_t)d*3072, nullptr, ff1b, BTn, 3072, 768, 1);
    gemm_pipe<2,2,4,4,true><<<dim3(BTn/128, 768/128), 256, 0, stream>>>(
        ff1b, w2T + (size_t)d*768*3072, b2 + (size_t)d*768, tmp, nullptr, BTn, 768, 3072, 0);
    ln_res_kernel<<<BTn, 256, 0, stream>>>(tmp, h, hb, ln2_g + (size_t)d*768, ln2_b + (size_t)d*768);
  }

  float* logits = (float*)d_out;
  gemm_pipe<2,4,8,4,false><<<dim3(BTn/256, Vn/256), 512, 0, stream>>>(
      hb, wlT, bl, logits, nullptr, BTn, Vn, 768, 0);
  loss_row_kernel<<<BTn, 256, 0, stream>>>(logits, y, loss_rows);
  loss_reduce_kernel<<<1, 256, 0, stream>>>(loss_rows, logits + (size_t)BTn*Vn);
}